// Round 1
// 1798.630 us; speedup vs baseline: 1.0222x; 1.0222x over previous
//
#include <hip/hip_runtime.h>

// TensorProduct: out[n,p3,k,f] = sum_{i,j} cg[i,j,k] * x1[n,p1,i,f]*x2[n,p2,j,f]
// with parity coupling: even = eee+ooe, odd = eoo+oeo.
// Parity-Karatsuba: s = couple(0.5*(a0+a1), b0+b1), d = couple(0.5*(a0-a1), b0-b1)
//   out_even = s+d, out_odd = s-d.
// CG sparsity (triangle rule) is compile-time known: valid k per (i,j) is the
// contiguous range [lo^2, (hi+1)^2).
//
// R1 change: split k-range into two passes (k<9: 18 accums; k>=9: 32 accums)
// to cut peak live VGPRs ~110-130 -> ~80 and raise occupancy 4 -> 5+ waves/SIMD.
// Pass-B products are recomputed (55 pairs, +4% VALU); an empty asm launders one
// operand so the compiler can't CSE them with pass-A products (which would keep
// them live and defeat the register reduction).

#define NN 50000
#define FF 128
#define NL1 9
#define NL2 9
#define NL3 25

__global__ __launch_bounds__(256, 5) void tp_kernel(
    const float* __restrict__ x1, const float* __restrict__ x2,
    const float* __restrict__ cg, float* __restrict__ out) {
  // l value of each flattened (l,m) slot
  constexpr int LOF[9] = {0, 1, 1, 1, 2, 2, 2, 2, 2};

  int tid = blockIdx.x * blockDim.x + threadIdx.x;
  int f = tid & (FF - 1);
  int n = tid >> 7;  // /128
  if (n >= NN) return;

  const float* p1 = x1 + ((size_t)n * 2 * NL1) * FF + f;
  const float* p2 = x2 + ((size_t)n * 2 * NL2) * FF + f;

  float as[NL1], ad[NL1], bs[NL2], bd[NL2];
#pragma unroll
  for (int i = 0; i < NL1; i++) {
    float e = p1[i * FF];
    float o = p1[(NL1 + i) * FF];
    as[i] = 0.5f * (e + o);
    ad[i] = 0.5f * (e - o);
  }
#pragma unroll
  for (int j = 0; j < NL2; j++) {
    float e = p2[j * FF];
    float o = p2[(NL2 + j) * FF];
    bs[j] = e + o;
    bd[j] = e - o;
  }

  float* po = out + ((size_t)n * 2 * NL3) * FF + f;

  // ---- pass A: k in [0,9)  (l3 <= 2), 615 terms, 18 accumulators ----
  {
    float s[9], d[9];
#pragma unroll
    for (int k = 0; k < 9; k++) { s[k] = 0.f; d[k] = 0.f; }
#pragma unroll
    for (int i = 0; i < NL1; i++) {
#pragma unroll
      for (int j = 0; j < NL2; j++) {
        int lo = LOF[i] - LOF[j]; if (lo < 0) lo = -lo;
        int hi = LOF[i] + LOF[j];
        int k0 = lo * lo;
        int k1 = (hi + 1) * (hi + 1);
        float ps = as[i] * bs[j];
        float pd = ad[i] * bd[j];
#pragma unroll
        for (int k = 0; k < 9; k++) {
          if (k >= k0 && k < k1) {  // compile-time after unroll
            float c = cg[(i * NL2 + j) * NL3 + k];  // uniform -> s_load
            s[k] = fmaf(c, ps, s[k]);
            d[k] = fmaf(c, pd, d[k]);
          }
        }
      }
    }
#pragma unroll
    for (int k = 0; k < 9; k++) {
      po[k * FF]         = s[k] + d[k];  // even
      po[(NL3 + k) * FF] = s[k] - d[k];  // odd
    }
  }

  // ---- pass B: k in [9,25) (l3 in {3,4}), 610 terms, 32 accumulators ----
  {
    float s[16], d[16];
#pragma unroll
    for (int k = 0; k < 16; k++) { s[k] = 0.f; d[k] = 0.f; }
#pragma unroll
    for (int i = 0; i < NL1; i++) {
#pragma unroll
      for (int j = 0; j < NL2; j++) {
        int lo = LOF[i] - LOF[j]; if (lo < 0) lo = -lo;
        int hi = LOF[i] + LOF[j];
        if (hi >= 3) {  // pair contributes to k>=9 (compile-time)
          int k0 = lo * lo; if (k0 < 9) k0 = 9;
          int k1 = (hi + 1) * (hi + 1);
          float av = as[i], cv = ad[i];
          asm("" : "+v"(av));  // block CSE with pass-A products (zero-cost)
          asm("" : "+v"(cv));
          float ps = av * bs[j];
          float pd = cv * bd[j];
#pragma unroll
          for (int k = 9; k < 25; k++) {
            if (k >= k0 && k < k1) {  // compile-time after unroll
              float c = cg[(i * NL2 + j) * NL3 + k];  // uniform -> s_load
              s[k - 9] = fmaf(c, ps, s[k - 9]);
              d[k - 9] = fmaf(c, pd, d[k - 9]);
            }
          }
        }
      }
    }
#pragma unroll
    for (int k = 9; k < 25; k++) {
      po[k * FF]         = s[k - 9] + d[k - 9];  // even
      po[(NL3 + k) * FF] = s[k - 9] - d[k - 9];  // odd
    }
  }
}

extern "C" void kernel_launch(void* const* d_in, const int* in_sizes, int n_in,
                              void* d_out, int out_size, void* d_ws, size_t ws_size,
                              hipStream_t stream) {
  const float* x1 = (const float*)d_in[0];
  const float* x2 = (const float*)d_in[1];
  const float* cg = (const float*)d_in[2];
  float* out = (float*)d_out;
  int total = NN * FF;              // 6,400,000 threads, one per (n,f)
  dim3 block(256);
  dim3 grid((total + 255) / 256);   // 25000 blocks
  tp_kernel<<<grid, block, 0, stream>>>(x1, x2, cg, out);
}